// Round 8
// baseline (282.692 us; speedup 1.0000x reference)
//
#include <hip/hip_runtime.h>
#include <hip/hip_bf16.h>

#define EMBED 1024
#define NH 16
#define HD 64
#define BSZ 4
#define SSZ 2048
#define LSTR 72   // LDS row stride (shorts); 144 B rows => 16B-aligned
#define BSTR 24   // qkv V-bounce stride (shorts); 48 B rows => 16B-aligned

typedef __attribute__((ext_vector_type(8))) short short8;
typedef __attribute__((ext_vector_type(4))) float float4v;
typedef __attribute__((ext_vector_type(2))) unsigned int uint2v;
typedef __attribute__((ext_vector_type(4))) unsigned int uint4v;

__device__ inline float4v mfma16(short8 a, short8 b, float4v c) {
    return __builtin_amdgcn_mfma_f32_16x16x32_bf16(a, b, c, 0, 0, 0);
}

__device__ inline float fexp2(float x) { return __builtin_amdgcn_exp2f(x); }

// pack two fp32 -> bf16x2 dword: round-half-up adds + v_perm byte-pack (3 VALU)
__device__ inline unsigned pk2(float a, float b) {
    unsigned ua = __builtin_bit_cast(unsigned, a) + 0x8000u;
    unsigned ub = __builtin_bit_cast(unsigned, b) + 0x8000u;
    return __builtin_amdgcn_perm(ub, ua, 0x07060302u);
}

// load 8 consecutive fp32 -> bf16 short8 fragment (4 perms)
__device__ inline short8 ld8_f32_bf16(const float* p) {
    float4v lo = *(const float4v*)p;
    float4v hi = *(const float4v*)(p + 4);
    uint4v u;
    u[0] = pk2(lo[0], lo[1]); u[1] = pk2(lo[2], lo[3]);
    u[2] = pk2(hi[0], hi[1]); u[3] = pk2(hi[2], hi[3]);
    return __builtin_bit_cast(short8, u);
}

// async global->LDS, 16B per lane
__device__ inline void glds16(const short* gsrc, short* ldst) {
    __builtin_amdgcn_global_load_lds(
        (const __attribute__((address_space(1))) unsigned int*)gsrc,
        (__attribute__((address_space(3))) unsigned int*)ldst,
        16, 0, 0);
}

// ---------------- Kernel 0: convert W_p (fp32) -> bf16 ----------------
__global__ __launch_bounds__(256) void wp_cvt_kernel(
    const float* __restrict__ Wp, short* __restrict__ Wpb)
{
    int i = (blockIdx.x * 256 + threadIdx.x) * 4;
    float4v v = *(const float4v*)(Wp + i);
    uint2v s;
    s[0] = pk2(v[0], v[1]);
    s[1] = pk2(v[2], v[3]);
    *(uint2v*)(Wpb + i) = s;
}

// ---------------- Kernel 1: QKV projection, head-streaming ----------------
// grid (512 row-tiles of 16, 3 tensors), block 256 (4 waves; each wave:
// same 16 rows, its own 4 heads). W staged once; Q/K computed transposed
// (A=W,B=X -> D rows = d) and stored directly; V via per-wave LDS bounce.
__global__ __launch_bounds__(256) void qkv_kernel(
    const float* __restrict__ q_in, const float* __restrict__ k_in,
    const float* __restrict__ v_in,
    const float* __restrict__ Wq, const float* __restrict__ bq,
    const float* __restrict__ Wk, const float* __restrict__ bk,
    const float* __restrict__ Wv, const float* __restrict__ bv,
    short* __restrict__ qp, short* __restrict__ kp, short* __restrict__ vt)
{
    __shared__ __align__(16) short Wb[64 * LSTR];
    __shared__ __align__(16) short Bnc[4][64 * BSTR];  // per-wave V bounce [d][s16]

    int z = blockIdx.y;
    const float* X    = z == 0 ? q_in : (z == 1 ? k_in : v_in);
    const float* W    = z == 0 ? Wq   : (z == 1 ? Wk   : Wv);
    const float* bias = z == 0 ? bq   : (z == 1 ? bk   : bv);
    const float scale = z == 0 ? 0.125f * 1.44269504f : 1.0f;

    int tid = threadIdx.x;
    int wave = tid >> 6, lane = tid & 63, quad = lane >> 4, l16 = lane & 15;
    int rbase = blockIdx.x * 16;          // global row base (b*S + s)
    int b = rbase >> 11;
    int sbase = rbase & (SSZ - 1);

    // stage W (64x64 fp32 -> bf16), 16 floats per thread
    {
        int wrow = tid >> 2, wc16 = (tid & 3) * 16;
        const float* wsrc = W + wrow * HD + wc16;
        *(short8*)&Wb[wrow * LSTR + wc16]     = ld8_f32_bf16(wsrc);
        *(short8*)&Wb[wrow * LSTR + wc16 + 8] = ld8_f32_bf16(wsrc + 8);
    }
    __syncthreads();

    // W fragments (loop-invariant): rows = l16-indexed
    short8 wf[4][2];
#pragma unroll
    for (int t = 0; t < 4; ++t)
#pragma unroll
        for (int c = 0; c < 2; ++c)
            wf[t][c] = *(const short8*)&Wb[(t * 16 + l16) * LSTR + c * 32 + quad * 8];

    const float* xrow = X + (size_t)(rbase + l16) * EMBED;

    if (z < 2) {
        short* Y = z == 0 ? qp : kp;
        float4v bv4[4];
#pragma unroll
        for (int dt = 0; dt < 4; ++dt)
            bv4[dt] = *(const float4v*)&bias[dt * 16 + quad * 4];
#pragma unroll
        for (int hh = 0; hh < 4; ++hh) {
            int h = wave * 4 + hh;
            const float* xs = xrow + h * HD + quad * 8;
            short8 xf0 = ld8_f32_bf16(xs);
            short8 xf1 = ld8_f32_bf16(xs + 32);
            float4v acc[4];
#pragma unroll
            for (int dt = 0; dt < 4; ++dt) acc[dt] = (float4v)(0.f);
#pragma unroll
            for (int dt = 0; dt < 4; ++dt) {
                acc[dt] = mfma16(wf[dt][0], xf0, acc[dt]);
                acc[dt] = mfma16(wf[dt][1], xf1, acc[dt]);
            }
            // D: row = d = quad*4+r, col = s = l16 -> direct b64 stores
            size_t ybase = ((size_t)(b * NH + h) * SSZ + sbase + l16) * HD;
#pragma unroll
            for (int dt = 0; dt < 4; ++dt) {
                float t0 = (acc[dt][0] + bv4[dt][0]) * scale;
                float t1 = (acc[dt][1] + bv4[dt][1]) * scale;
                float t2 = (acc[dt][2] + bv4[dt][2]) * scale;
                float t3 = (acc[dt][3] + bv4[dt][3]) * scale;
                uint2v p; p[0] = pk2(t0, t1); p[1] = pk2(t2, t3);
                *(uint2v*)&Y[ybase + dt * 16 + quad * 4] = p;
            }
        }
    } else {
        short* bw = &Bnc[wave][0];
        float bvs[4];
#pragma unroll
        for (int nt = 0; nt < 4; ++nt) bvs[nt] = bias[nt * 16 + l16];
#pragma unroll
        for (int hh = 0; hh < 4; ++hh) {
            int h = wave * 4 + hh;
            const float* xs = xrow + h * HD + quad * 8;
            short8 xf0 = ld8_f32_bf16(xs);
            short8 xf1 = ld8_f32_bf16(xs + 32);
            float4v acc[4];
#pragma unroll
            for (int nt = 0; nt < 4; ++nt) acc[nt] = (float4v)(0.f);
#pragma unroll
            for (int nt = 0; nt < 4; ++nt) {
                acc[nt] = mfma16(xf0, wf[nt][0], acc[nt]);
                acc[nt] = mfma16(xf1, wf[nt][1], acc[nt]);
            }
            // D: row = s = quad*4+r, col = d = nt*16+l16 -> bounce [d][s16]
#pragma unroll
            for (int nt = 0; nt < 4; ++nt) {
                float t0 = acc[nt][0] + bvs[nt];
                float t1 = acc[nt][1] + bvs[nt];
                float t2 = acc[nt][2] + bvs[nt];
                float t3 = acc[nt][3] + bvs[nt];
                uint2v p; p[0] = pk2(t0, t1); p[1] = pk2(t2, t3);
                *(uint2v*)&bw[(nt * 16 + l16) * BSTR + quad * 4] = p;
            }
            // within-wave readback (compiler orders via lgkmcnt): lane = d
            short8 v0 = *(const short8*)&bw[lane * BSTR];
            short8 v1 = *(const short8*)&bw[lane * BSTR + 8];
            size_t o = ((size_t)(b * NH + h) * HD + lane) * SSZ + sbase;
            *(short8*)&vt[o] = v0;
            *(short8*)&vt[o + 8] = v1;
        }
    }
}

// ---------------- Kernel 2: flash attention (LDS K/V + reg prefetch) -------
__global__ __launch_bounds__(512, 4) void attn_kernel(
    const short* __restrict__ qp, const short* __restrict__ kp,
    const short* __restrict__ vt, short* __restrict__ ctx)
{
    __shared__ __align__(16) short Kls[64 * LSTR];
    __shared__ __align__(16) short Vls[64 * LSTR];
    __shared__ __align__(16) short Pl[8 * 32 * LSTR];

    int tid = threadIdx.x;
    int wave = tid >> 6, lane = tid & 63, quad = lane >> 4, l16 = lane & 15;
    int bh = blockIdx.x;
    int b = bh >> 4, h = bh & 15;
    int qrow0 = blockIdx.y * 256 + wave * 32;

    const short* Qb = qp + (size_t)bh * SSZ * HD;
    const short* Kb = kp + (size_t)bh * SSZ * HD;
    const short* Vb = vt + (size_t)bh * HD * SSZ;

    int srow = tid >> 3;
    int scol = (tid & 7) * 8;
    const short* ksrc = Kb + srow * HD + scol;
    const short* vsrc = Vb + (size_t)srow * SSZ + scol;
    short* kdst = &Kls[srow * LSTR + scol];
    short* vdst = &Vls[srow * LSTR + scol];

    short8 qf[2][2];
#pragma unroll
    for (int nt = 0; nt < 2; ++nt)
#pragma unroll
        for (int c = 0; c < 2; ++c)
            qf[nt][c] = *(const short8*)&Qb[(size_t)(qrow0 + nt * 16 + l16) * HD + c * 32 + quad * 8];

    const short one = (short)0x3F80;
    short8 ones = {one, one, one, one, one, one, one, one};

    float4v oacc[4][2];
#pragma unroll
    for (int dt = 0; dt < 4; ++dt)
#pragma unroll
        for (int nt = 0; nt < 2; ++nt) oacc[dt][nt] = (float4v)(0.f);
    float4v lacc[2];
    lacc[0] = (float4v)(0.f); lacc[1] = (float4v)(0.f);

    short* Pw = Pl + wave * 32 * LSTR;

    {
        short8 kr = *(const short8*)(ksrc);
        short8 vr = *(const short8*)(vsrc);
        *(short8*)kdst = kr;
        *(short8*)vdst = vr;
    }
    __syncthreads();

    for (int kt = 0; kt < SSZ / 64; ++kt) {
        short8 krn, vrn;
        if (kt < 31) {
            krn = *(const short8*)(ksrc + (kt + 1) * 64 * HD);
            vrn = *(const short8*)(vsrc + (kt + 1) * 64);
        }
        float4v sacc[4][2];
#pragma unroll
        for (int mt = 0; mt < 4; ++mt) {
            sacc[mt][0] = (float4v)(0.f); sacc[mt][1] = (float4v)(0.f);
        }
#pragma unroll
        for (int mt = 0; mt < 4; ++mt)
#pragma unroll
            for (int c = 0; c < 2; ++c) {
                short8 kf = *(const short8*)&Kls[(mt * 16 + l16) * LSTR + c * 32 + quad * 8];
                sacc[mt][0] = mfma16(kf, qf[0][c], sacc[mt][0]);
                sacc[mt][1] = mfma16(kf, qf[1][c], sacc[mt][1]);
            }
#pragma unroll
        for (int mt = 0; mt < 4; ++mt)
#pragma unroll
            for (int nt = 0; nt < 2; ++nt) {
                float e0 = fexp2(sacc[mt][nt][0]);
                float e1 = fexp2(sacc[mt][nt][1]);
                float e2 = fexp2(sacc[mt][nt][2]);
                float e3 = fexp2(sacc[mt][nt][3]);
                uint2v p; p[0] = pk2(e0, e1); p[1] = pk2(e2, e3);
                *(uint2v*)&Pw[(nt * 16 + l16) * LSTR + mt * 16 + quad * 4] = p;
            }
        short8 pf[2][2];
#pragma unroll
        for (int nt = 0; nt < 2; ++nt)
#pragma unroll
            for (int c = 0; c < 2; ++c)
                pf[nt][c] = *(const short8*)&Pw[(nt * 16 + l16) * LSTR + c * 32 + quad * 8];
#pragma unroll
        for (int nt = 0; nt < 2; ++nt)
#pragma unroll
            for (int c = 0; c < 2; ++c)
                lacc[nt] = mfma16(ones, pf[nt][c], lacc[nt]);
#pragma unroll
        for (int dt = 0; dt < 4; ++dt)
#pragma unroll
            for (int c = 0; c < 2; ++c) {
                short8 vf = *(const short8*)&Vls[(dt * 16 + l16) * LSTR + c * 32 + quad * 8];
                oacc[dt][0] = mfma16(vf, pf[0][c], oacc[dt][0]);
                oacc[dt][1] = mfma16(vf, pf[1][c], oacc[dt][1]);
            }
        __syncthreads();
        if (kt < 31) {
            *(short8*)kdst = krn;
            *(short8*)vdst = vrn;
        }
        __syncthreads();
    }
    float rl[2];
    rl[0] = 1.0f / lacc[0][0];
    rl[1] = 1.0f / lacc[1][0];
#pragma unroll
    for (int dt = 0; dt < 4; ++dt)
#pragma unroll
        for (int nt = 0; nt < 2; ++nt) {
            uint2v p;
            p[0] = pk2(oacc[dt][nt][0] * rl[nt], oacc[dt][nt][1] * rl[nt]);
            p[1] = pk2(oacc[dt][nt][2] * rl[nt], oacc[dt][nt][3] * rl[nt]);
            size_t o = ((size_t)(b * SSZ + qrow0 + nt * 16 + l16)) * EMBED
                       + h * HD + dt * 16 + quad * 4;
            *(uint2v*)&ctx[o] = p;
        }
}

// ---------------- Kernel 3: output projection (m97-style, glds staging) ----
__global__ __launch_bounds__(256) void proj_kernel(
    const short* __restrict__ ctx, const short* __restrict__ Wpb,
    const float* __restrict__ bp, float* __restrict__ out)
{
    __shared__ __align__(16) short Als[128 * 64];
    __shared__ __align__(16) short Bls[128 * 64];

    int tid = threadIdx.x;
    int wave = tid >> 6, lane = tid & 63, quad = lane >> 4, l16 = lane & 15;
    int wm = wave >> 1, wn = wave & 1;
    int row0 = blockIdx.x * 128;
    int col0 = blockIdx.y * 128;

    int lrow = lane >> 3;
    int lcol = (lane & 7) * 8;
    const short* ag = ctx + (size_t)(row0 + wave * 32 + lrow) * EMBED + lcol;
    const short* bg = Wpb + (size_t)(col0 + wave * 32 + lrow) * EMBED + lcol;

    float4v acc[4][4];
#pragma unroll
    for (int mt = 0; mt < 4; ++mt)
#pragma unroll
        for (int nt = 0; nt < 4; ++nt) acc[mt][nt] = (float4v)(0.f);

    for (int kc = 0; kc < EMBED / 64; ++kc) {
#pragma unroll
        for (int i = 0; i < 4; ++i) {
            glds16(ag + (size_t)(i * 8) * EMBED + kc * 64,
                   &Als[(wave * 32 + i * 8) * 64]);
            glds16(bg + (size_t)(i * 8) * EMBED + kc * 64,
                   &Bls[(wave * 32 + i * 8) * 64]);
        }
        __syncthreads();
#pragma unroll
        for (int ks = 0; ks < 2; ++ks) {
            short8 af[4], bf[4];
#pragma unroll
            for (int mt = 0; mt < 4; ++mt)
                af[mt] = *(const short8*)&Als[(wm * 64 + mt * 16 + l16) * 64 + ks * 32 + quad * 8];
#pragma unroll
            for (int nt = 0; nt < 4; ++nt)
                bf[nt] = *(const short8*)&Bls[(wn * 64 + nt * 16 + l16) * 64 + ks * 32 + quad * 8];
#pragma unroll
            for (int mt = 0; mt < 4; ++mt)
#pragma unroll
                for (int nt = 0; nt < 4; ++nt)
                    acc[mt][nt] = mfma16(af[mt], bf[nt], acc[mt][nt]);
        }
        __syncthreads();
    }
#pragma unroll
    for (int nt = 0; nt < 4; ++nt) {
        float bias = bp[col0 + wn * 64 + nt * 16 + l16];
#pragma unroll
        for (int mt = 0; mt < 4; ++mt)
#pragma unroll
            for (int r = 0; r < 4; ++r) {
                int row = row0 + wm * 64 + mt * 16 + quad * 4 + r;
                out[(size_t)row * EMBED + col0 + wn * 64 + nt * 16 + l16] = acc[mt][nt][r] + bias;
            }
    }
}

extern "C" void kernel_launch(void* const* d_in, const int* in_sizes, int n_in,
                              void* d_out, int out_size, void* d_ws, size_t ws_size,
                              hipStream_t stream) {
    const float* q_in = (const float*)d_in[0];
    const float* k_in = (const float*)d_in[1];
    const float* v_in = (const float*)d_in[2];
    const float* Wq   = (const float*)d_in[3];
    const float* bq   = (const float*)d_in[4];
    const float* Wk   = (const float*)d_in[5];
    const float* bk   = (const float*)d_in[6];
    const float* Wv   = (const float*)d_in[7];
    const float* bv   = (const float*)d_in[8];
    const float* Wp   = (const float*)d_in[9];
    const float* bp   = (const float*)d_in[10];

    const size_t TENS = (size_t)BSZ * SSZ * EMBED;
    short* ws  = (short*)d_ws;
    short* qp  = ws;
    short* kp  = qp + TENS;
    short* vtp = kp + TENS;
    short* ctx = vtp + TENS;
    short* wpb = ctx + TENS;

    wp_cvt_kernel<<<dim3(EMBED * EMBED / 1024), 256, 0, stream>>>(Wp, wpb);
    qkv_kernel<<<dim3(BSZ * SSZ / 16, 3), 256, 0, stream>>>(
        q_in, k_in, v_in, Wq, bq, Wk, bk, Wv, bv, qp, kp, vtp);
    attn_kernel<<<dim3(BSZ * NH, SSZ / 256), 512, 0, stream>>>(qp, kp, vtp, ctx);
    proj_kernel<<<dim3(BSZ * SSZ / 128, EMBED / 128), 256, 0, stream>>>(
        ctx, wpb, bp, (float*)d_out);
}